// Round 8
// baseline (343.418 us; speedup 1.0000x reference)
//
#include <hip/hip_runtime.h>

#define SEQ 4096
#define DIM 128
#define BK 64
#define KSTR 136   // 128+8 fp16; row 272 B; QK reads land 2-way on banks (free)
#define PSTR 72    // 64+8
#define VSTRP 72   // prepass transpose tile stride (shorts)

// workspace layout (bytes)
#define KH_SZ  (8ull * SEQ * DIM * 2)            // 8.39 MB fp16 K
#define PART   (8ull * SEQ * DIM * 4)            // 16.78 MB fp32 partial numerator per split
#define LPS    (8ull * SEQ * 4)                  // 0.13 MB per split

typedef __attribute__((ext_vector_type(8))) _Float16 half8;
typedef __attribute__((ext_vector_type(2))) __fp16   fp16x2;
typedef __attribute__((ext_vector_type(4))) float  float4v;
typedef __attribute__((ext_vector_type(4))) unsigned int uint4v;
typedef __attribute__((ext_vector_type(2))) unsigned int uint2v;

static __device__ __forceinline__ unsigned int pkh(float a, float b) {
    fp16x2 h = __builtin_amdgcn_cvt_pkrtz(a, b);
    return __builtin_bit_cast(unsigned int, h);
}

// ---------------- prepass: K -> fp16 [b][s][d]; V -> fp16 transposed [b][d][s] ----------------
__global__ __launch_bounds__(256)
void prepass(const float* __restrict__ Kg, const float* __restrict__ Vg,
             short* __restrict__ Kh, short* __restrict__ VtG) {
    __shared__ short Ts[DIM * VSTRP];
    const int t  = threadIdx.x;
    const int b  = blockIdx.x & 7;
    const int s0 = (blockIdx.x >> 3) * 64;

    {   // K tile: 64 rows x 128 fp32 -> fp16, coalesced
        const float4v* src = (const float4v*)(Kg + ((size_t)b * SEQ + s0) * DIM);
        uint4v* dst = (uint4v*)(Kh + ((size_t)b * SEQ + s0) * DIM);
        #pragma unroll
        for (int j = 0; j < 4; ++j) {
            int idx = j * 256 + t;
            float4v x0 = src[idx * 2];
            float4v x1 = src[idx * 2 + 1];
            uint4v u;
            u[0] = pkh(x0[0], x0[1]); u[1] = pkh(x0[2], x0[3]);
            u[2] = pkh(x1[0], x1[1]); u[3] = pkh(x1[2], x1[3]);
            dst[idx] = u;
        }
    }
    {   // V tile: each thread 4 keys x 8 d -> Ts[d][key] (b64 writes, ~4-way)
        const int key4 = (t & 15) * 4;
        const int d0   = (t >> 4) * 8;
        const float* Vsrc = Vg + ((size_t)b * SEQ + s0) * DIM;
        float4v a[4][2];
        #pragma unroll
        for (int i = 0; i < 4; ++i) {
            a[i][0] = *(const float4v*)&Vsrc[(key4 + i) * DIM + d0];
            a[i][1] = *(const float4v*)&Vsrc[(key4 + i) * DIM + d0 + 4];
        }
        #pragma unroll
        for (int jj = 0; jj < 2; ++jj) {
            #pragma unroll
            for (int e = 0; e < 4; ++e) {
                int d = d0 + jj * 4 + e;
                uint2v pk;
                pk[0] = pkh(a[0][jj][e], a[1][jj][e]);
                pk[1] = pkh(a[2][jj][e], a[3][jj][e]);
                *(uint2v*)&Ts[d * VSTRP + key4] = pk;
            }
        }
    }
    __syncthreads();
    // read phase XOR-swizzled: chunk cc=(c+d)&7 -> 2-way banks instead of 8-way
    #pragma unroll
    for (int j = 0; j < 4; ++j) {
        int idx = j * 256 + t;
        int d = idx >> 3;
        int c = idx & 7;
        int cc = (c + d) & 7;
        uint4v val = *(const uint4v*)&Ts[d * VSTRP + cc * 8];
        *(uint4v*)(VtG + ((size_t)b * DIM + d) * SEQ + s0 + cc * 8) = val;
    }
}

// ---------------- main: 128-thr blocks; K in LDS, V direct from L2; split-K x NS ----------------
template<int NS>
__global__ __launch_bounds__(128, 3)
void attn_fa6(const float* __restrict__ Qg, const short* __restrict__ Kh,
              const short* __restrict__ VtG, float* __restrict__ Op,
              float* __restrict__ lp) {
    __shared__ short Ks[BK * KSTR];   // 17408 B
    __shared__ short Ps[BK * PSTR];   //  9216 B (separate: no mid-iter barrier)

    const int t    = threadIdx.x;
    const int w    = t >> 6;
    const int lane = t & 63;
    const int l15  = lane & 15;
    const int quad = lane >> 4;
    const int q8   = quad * 8;
    const int wq   = w * 32;
    const int tr = t >> 4, tc = t & 15;   // K staging coords

    const int b     = blockIdx.x & 7;                 // XCD-sticky batch
    const int split = (blockIdx.x >> 3) % NS;
    const int qbase = (blockIdx.x / (8 * NS)) * 64;

    const float qs = 0.08838834764831845f * 1.44269504088896340f; // 1/sqrt(128)*log2(e)

    // Q fragments (pre-scaled fp16), register-resident
    half8 qf[2][4];
    {
        const float* Qb = Qg + ((size_t)b * SEQ + qbase + wq) * DIM;
        #pragma unroll
        for (int m = 0; m < 2; ++m) {
            const float* qrow = Qb + (m * 16 + l15) * DIM;
            #pragma unroll
            for (int k = 0; k < 4; ++k) {
                float4v x0 = *(const float4v*)(qrow + k * 32 + q8);
                float4v x1 = *(const float4v*)(qrow + k * 32 + q8 + 4);
                uint4v u;
                u[0] = pkh(x0[0] * qs, x0[1] * qs);
                u[1] = pkh(x0[2] * qs, x0[3] * qs);
                u[2] = pkh(x1[0] * qs, x1[1] * qs);
                u[3] = pkh(x1[2] * qs, x1[3] * qs);
                qf[m][k] = __builtin_bit_cast(half8, u);
            }
        }
    }

    const float4v zero4 = {0.0f, 0.0f, 0.0f, 0.0f};
    float4v o_acc[2][8];
    float4v l_part[2];
    #pragma unroll
    for (int m = 0; m < 2; ++m) {
        l_part[m] = zero4;
        #pragma unroll
        for (int n = 0; n < 8; ++n) o_acc[m][n] = zero4;
    }

    const short* Khb = Kh + (size_t)b * SEQ * DIM;
    const short* Vtb = VtG + (size_t)b * DIM * SEQ;

    const int kt0 = split * (64 / NS);
    const int kt1 = kt0 + (64 / NS);

    for (int kt = kt0; kt < kt1; ++kt) {
        const int kbase = kt * BK;

        // stage K tile 64x128 fp16 (straight copy; no prefetch regs — TLP hides it)
        #pragma unroll
        for (int j = 0; j < 8; ++j) {
            uint4v v = *(const uint4v*)(Khb + (size_t)(kbase + j * 8 + tr) * DIM + tc * 8);
            *(uint4v*)&Ks[(j * 8 + tr) * KSTR + tc * 8] = v;
        }
        __syncthreads();   // A: stage visible to all waves

        // S = Q K^T
        float4v s[2][4];
        #pragma unroll
        for (int m = 0; m < 2; ++m)
            #pragma unroll
            for (int nt = 0; nt < 4; ++nt) s[m][nt] = zero4;
        #pragma unroll
        for (int k = 0; k < 4; ++k) {
            #pragma unroll
            for (int nt = 0; nt < 4; ++nt) {
                half8 bk = *(const half8*)&Ks[(nt * 16 + l15) * KSTR + k * 32 + q8];
                s[0][nt] = __builtin_amdgcn_mfma_f32_16x16x32_f16(qf[0][k], bk, s[0][nt], 0, 0, 0);
                s[1][nt] = __builtin_amdgcn_mfma_f32_16x16x32_f16(qf[1][k], bk, s[1][nt], 0, 0, 0);
            }
        }

        // P = exp2(S), partial l, stage P fp16 (separate buffer, wave-local rows)
        #pragma unroll
        for (int m = 0; m < 2; ++m) {
            const int rowb = wq + m * 16 + quad * 4;
            #pragma unroll
            for (int nt = 0; nt < 4; ++nt) {
                const int colo = nt * 16 + l15;
                #pragma unroll
                for (int r = 0; r < 4; r += 2) {
                    float p0 = __builtin_amdgcn_exp2f(s[m][nt][r]);
                    float p1 = __builtin_amdgcn_exp2f(s[m][nt][r + 1]);
                    l_part[m][r]     += p0;
                    l_part[m][r + 1] += p1;
                    unsigned int u = pkh(p0, p1);
                    Ps[(rowb + r)     * PSTR + colo] = (short)(u & 0xFFFFu);
                    Ps[(rowb + r + 1) * PSTR + colo] = (short)(u >> 16);
                }
            }
        }
        __syncthreads();   // B: all Ks reads done -> next iter may restage

        // O += P V : A from Ps (wave-local), B direct from L2-resident Vt workspace
        #pragma unroll
        for (int k2 = 0; k2 < 2; ++k2) {
            half8 a0 = *(const half8*)&Ps[(wq + l15) * PSTR + k2 * 32 + q8];
            half8 a1 = *(const half8*)&Ps[(wq + 16 + l15) * PSTR + k2 * 32 + q8];
            const short* vcol = Vtb + kbase + k2 * 32 + q8;
            #pragma unroll
            for (int nt2 = 0; nt2 < 8; ++nt2) {
                half8 bv = *(const half8*)(vcol + (size_t)(nt2 * 16 + l15) * SEQ);
                o_acc[0][nt2] = __builtin_amdgcn_mfma_f32_16x16x32_f16(a0, bv, o_acc[0][nt2], 0, 0, 0);
                o_acc[1][nt2] = __builtin_amdgcn_mfma_f32_16x16x32_f16(a1, bv, o_acc[1][nt2], 0, 0, 0);
            }
        }
    }

    // epilogue: reduce l over 16 lanes, store UNNORMALIZED partials + l
    #pragma unroll
    for (int m = 0; m < 2; ++m) {
        float4v l = l_part[m];
        #pragma unroll
        for (int off = 1; off <= 8; off <<= 1) {
            l[0] += __shfl_xor(l[0], off);
            l[1] += __shfl_xor(l[1], off);
            l[2] += __shfl_xor(l[2], off);
            l[3] += __shfl_xor(l[3], off);
        }
        const int row0 = qbase + wq + m * 16 + quad * 4;
        float* Ob = Op + (((size_t)split * 8 + b) * SEQ + row0) * DIM;
        #pragma unroll
        for (int r = 0; r < 4; ++r) {
            #pragma unroll
            for (int nt2 = 0; nt2 < 8; ++nt2)
                Ob[r * DIM + nt2 * 16 + l15] = o_acc[m][nt2][r];
        }
        if (l15 == 0) {
            #pragma unroll
            for (int r = 0; r < 4; ++r)
                lp[((size_t)split * 8 + b) * SEQ + row0 + r] = l[r];
        }
    }
}

// ---------------- combine: O = sum(n_s) / sum(l_s) ----------------
template<int NS>
__global__ __launch_bounds__(256)
void combineNS(const float4v* __restrict__ Op, const float* __restrict__ lp,
               float4v* __restrict__ Out) {
    const size_t idx = (size_t)blockIdx.x * 256 + threadIdx.x;   // float4 units
    const size_t srow = idx >> 5;                                // (b*SEQ + q)
    float l = 0.0f;
    float4v n = {0.0f, 0.0f, 0.0f, 0.0f};
    #pragma unroll
    for (int s = 0; s < NS; ++s) {
        l += lp[(size_t)s * 8 * SEQ + srow];
        float4v c = Op[idx + (size_t)s * (8ull * SEQ * DIM / 4)];
        n[0] += c[0]; n[1] += c[1]; n[2] += c[2]; n[3] += c[3];
    }
    float inv = 1.0f / l;
    float4v o = {n[0] * inv, n[1] * inv, n[2] * inv, n[3] * inv};
    Out[idx] = o;
}

extern "C" void kernel_launch(void* const* d_in, const int* in_sizes, int n_in,
                              void* d_out, int out_size, void* d_ws, size_t ws_size,
                              hipStream_t stream) {
    const float* Q = (const float*)d_in[0];
    const float* K = (const float*)d_in[1];
    const float* V = (const float*)d_in[2];
    float* O = (float*)d_out;
    char* ws = (char*)d_ws;

    short* Kh  = (short*)ws;
    short* VtG = (short*)(ws + KH_SZ);
    char*  rest = ws + 2 * KH_SZ;

    const size_t need4 = 2 * KH_SZ + 4 * PART + 4 * LPS;

    prepass<<<dim3(8 * (SEQ / 64)), dim3(256), 0, stream>>>(K, V, Kh, VtG);

    if (ws_size >= need4) {
        float* Op = (float*)rest;
        float* lpp = (float*)(rest + 4 * PART);
        attn_fa6<4><<<dim3(8 * 4 * (SEQ / 64)), dim3(128), 0, stream>>>(Q, Kh, VtG, Op, lpp);
        combineNS<4><<<dim3((8 * SEQ * DIM / 4) / 256), dim3(256), 0, stream>>>(
            (const float4v*)Op, lpp, (float4v*)O);
    } else {
        float* Op = (float*)rest;
        float* lpp = (float*)(rest + 2 * PART);
        attn_fa6<2><<<dim3(8 * 2 * (SEQ / 64)), dim3(128), 0, stream>>>(Q, Kh, VtG, Op, lpp);
        combineNS<2><<<dim3((8 * SEQ * DIM / 4) / 256), dim3(256), 0, stream>>>(
            (const float4v*)Op, lpp, (float4v*)O);
    }
}

// Round 9
// 273.930 us; speedup vs baseline: 1.2537x; 1.2537x over previous
//
#include <hip/hip_runtime.h>

#define SEQ 4096
#define DIM 128
#define BK 64
#define KSTR 136   // 128+8 fp16; row 272 B
#define VSTR 72    // 64+8 fp16
#define VSTRP 72   // prepass transpose tile stride

// workspace layout (bytes)
#define KH_SZ  (8ull * SEQ * DIM * 2)            // 8.39 MB fp16 K
#define PART   (8ull * SEQ * DIM * 4)            // 16.78 MB fp32 partials per split
#define LPS    (8ull * SEQ * 4)

typedef __attribute__((ext_vector_type(8))) _Float16 half8;
typedef __attribute__((ext_vector_type(4))) _Float16 half4;
typedef __attribute__((ext_vector_type(2))) __fp16   fp16x2;
typedef __attribute__((ext_vector_type(4))) float  float4v;
typedef __attribute__((ext_vector_type(4))) unsigned int uint4v;
typedef __attribute__((ext_vector_type(2))) unsigned int uint2v;

static __device__ __forceinline__ unsigned int pkh(float a, float b) {
    fp16x2 h = __builtin_amdgcn_cvt_pkrtz(a, b);
    return __builtin_bit_cast(unsigned int, h);
}

// ---------------- prepass: K -> fp16 [b][s][d]; V -> fp16 transposed [b][d][s] ----------------
__global__ __launch_bounds__(256)
void prepass(const float* __restrict__ Kg, const float* __restrict__ Vg,
             short* __restrict__ Kh, short* __restrict__ VtG) {
    __shared__ short Ts[DIM * VSTRP];
    const int t  = threadIdx.x;
    const int b  = blockIdx.x & 7;
    const int s0 = (blockIdx.x >> 3) * 64;

    {   // K tile: coalesced fp32 -> fp16
        const float4v* src = (const float4v*)(Kg + ((size_t)b * SEQ + s0) * DIM);
        uint4v* dst = (uint4v*)(Kh + ((size_t)b * SEQ + s0) * DIM);
        #pragma unroll
        for (int j = 0; j < 4; ++j) {
            int idx = j * 256 + t;
            float4v x0 = src[idx * 2];
            float4v x1 = src[idx * 2 + 1];
            uint4v u;
            u[0] = pkh(x0[0], x0[1]); u[1] = pkh(x0[2], x0[3]);
            u[2] = pkh(x1[0], x1[1]); u[3] = pkh(x1[2], x1[3]);
            dst[idx] = u;
        }
    }
    {   // V tile: 4 keys x 8 d per thread -> Ts[d][key] (b64 writes, ~4-way)
        const int key4 = (t & 15) * 4;
        const int d0   = (t >> 4) * 8;
        const float* Vsrc = Vg + ((size_t)b * SEQ + s0) * DIM;
        float4v a[4][2];
        #pragma unroll
        for (int i = 0; i < 4; ++i) {
            a[i][0] = *(const float4v*)&Vsrc[(key4 + i) * DIM + d0];
            a[i][1] = *(const float4v*)&Vsrc[(key4 + i) * DIM + d0 + 4];
        }
        #pragma unroll
        for (int jj = 0; jj < 2; ++jj) {
            #pragma unroll
            for (int e = 0; e < 4; ++e) {
                int d = d0 + jj * 4 + e;
                uint2v pk;
                pk[0] = pkh(a[0][jj][e], a[1][jj][e]);
                pk[1] = pkh(a[2][jj][e], a[3][jj][e]);
                *(uint2v*)&Ts[d * VSTRP + key4] = pk;
            }
        }
    }
    __syncthreads();
    #pragma unroll
    for (int j = 0; j < 4; ++j) {   // XOR-swizzled read: ~2-way banks
        int idx = j * 256 + t;
        int d = idx >> 3;
        int c = idx & 7;
        int cc = (c + d) & 7;
        uint4v val = *(const uint4v*)&Ts[d * VSTRP + cc * 8];
        *(uint4v*)(VtG + ((size_t)b * DIM + d) * SEQ + s0 + cc * 8) = val;
    }
}

// ---- main: 2 waves x 64 q-rows; S^T = K Q^T, P^T stays in regs, O^T = V^T P^T ----
template<int NS>
__global__ __launch_bounds__(128, 2)
void attn_fa7(const float* __restrict__ Qg, const short* __restrict__ Kh,
              const short* __restrict__ VtG, float* __restrict__ Op,
              float* __restrict__ lp) {
    __shared__ short Ks[BK * KSTR];   // 17408 B
    __shared__ short Vt[DIM * VSTR];  // 18432 B

    const int t    = threadIdx.x;
    const int w    = t >> 6;
    const int lane = t & 63;
    const int l15  = lane & 15;
    const int quad = lane >> 4;
    const int q8   = quad * 8;
    const int q4   = quad * 4;
    const int wq   = w * 64;              // this wave's q base (64 rows)
    const int tr = t >> 4, tc = t & 15;   // K staging
    const int td = t >> 3, vc = t & 7;    // V staging

    const int b     = blockIdx.x & 7;
    const int split = (blockIdx.x >> 3) % NS;
    const int qbase = (blockIdx.x / (8 * NS)) * 128;

    const float qs = 0.08838834764831845f * 1.44269504088896340f; // 1/sqrt(128)*log2(e)

    // Q fragments (B-operand layout: n=q=l15, k=dim q8+j), pre-scaled fp16
    half8 qf[4][4];
    {
        const float* Qb = Qg + ((size_t)b * SEQ + qbase + wq) * DIM;
        #pragma unroll
        for (int nt = 0; nt < 4; ++nt) {
            const float* qrow = Qb + (nt * 16 + l15) * DIM;
            #pragma unroll
            for (int kc = 0; kc < 4; ++kc) {
                float4v x0 = *(const float4v*)(qrow + kc * 32 + q8);
                float4v x1 = *(const float4v*)(qrow + kc * 32 + q8 + 4);
                uint4v u;
                u[0] = pkh(x0[0] * qs, x0[1] * qs);
                u[1] = pkh(x0[2] * qs, x0[3] * qs);
                u[2] = pkh(x1[0] * qs, x1[1] * qs);
                u[3] = pkh(x1[2] * qs, x1[3] * qs);
                qf[nt][kc] = __builtin_bit_cast(half8, u);
            }
        }
    }

    const float4v zero4 = {0.0f, 0.0f, 0.0f, 0.0f};
    float4v o_acc[8][4];        // O^T tiles: [d-tile][q-tile], lane: q=l15, d=q4+r
    float  lacc[4] = {0.f, 0.f, 0.f, 0.f};
    #pragma unroll
    for (int dt = 0; dt < 8; ++dt)
        #pragma unroll
        for (int nt = 0; nt < 4; ++nt) o_acc[dt][nt] = zero4;

    const short* Khb = Kh + (size_t)b * SEQ * DIM;
    const short* Vtb = VtG + (size_t)b * DIM * SEQ;

    for (int kt = 0; kt < 64 / NS; ++kt) {
        const int kbase = (split * (64 / NS) + kt) * BK;

        // stage K 64x128 + Vt 128x64 (fp16 straight copies, 8 x 16B each per thread)
        #pragma unroll
        for (int j = 0; j < 8; ++j) {
            uint4v v = *(const uint4v*)(Khb + (size_t)(kbase + j * 8 + tr) * DIM + tc * 8);
            *(uint4v*)&Ks[(j * 8 + tr) * KSTR + tc * 8] = v;
        }
        #pragma unroll
        for (int j = 0; j < 8; ++j) {
            uint4v v = *(const uint4v*)(Vtb + (size_t)(j * 16 + td) * SEQ + kbase + vc * 8);
            *(uint4v*)&Vt[(j * 16 + td) * VSTR + vc * 8] = v;
        }
        __syncthreads();

        #pragma unroll
        for (int mt = 0; mt < 4; ++mt) {      // 16-key sub-tile
            // S^T = K Q^T : C lane: q=l15 (col), keys=q4+r (rows)
            float4v s[4];
            #pragma unroll
            for (int nt = 0; nt < 4; ++nt) s[nt] = zero4;
            #pragma unroll
            for (int kc = 0; kc < 4; ++kc) {
                half8 ak = *(const half8*)&Ks[(mt * 16 + l15) * KSTR + kc * 32 + q8];
                #pragma unroll
                for (int nt = 0; nt < 4; ++nt)
                    s[nt] = __builtin_amdgcn_mfma_f32_16x16x32_f16(ak, qf[nt][kc], s[nt], 0, 0, 0);
            }
            // P^T = exp2(S^T): regs ARE the 16x16x16 B-operand (k=q4+j == rows q4+r)
            uint2v pb[4];
            #pragma unroll
            for (int nt = 0; nt < 4; ++nt) {
                float p0 = __builtin_amdgcn_exp2f(s[nt][0]);
                float p1 = __builtin_amdgcn_exp2f(s[nt][1]);
                float p2 = __builtin_amdgcn_exp2f(s[nt][2]);
                float p3 = __builtin_amdgcn_exp2f(s[nt][3]);
                lacc[nt] += (p0 + p1) + (p2 + p3);
                pb[nt][0] = pkh(p0, p1);
                pb[nt][1] = pkh(p2, p3);
            }
            // O^T += V^T P^T : A = Vt[d=l15 rows][keys q4+j]
            #pragma unroll
            for (int dt = 0; dt < 8; ++dt) {
                half4 av = *(const half4*)&Vt[(dt * 16 + l15) * VSTR + mt * 16 + q4];
                #pragma unroll
                for (int nt = 0; nt < 4; ++nt)
                    o_acc[dt][nt] = __builtin_amdgcn_mfma_f32_16x16x16f16(
                        av, __builtin_bit_cast(half4, pb[nt]), o_acc[dt][nt], 0, 0, 0);
            }
        }
        __syncthreads();   // all LDS reads done -> next iter may restage
    }

    // epilogue: l = quad-reduce(lacc); store unnormalized O^T partials + l
    float* Opb = Op + ((size_t)(split * 8 + b) * SEQ) * DIM;
    #pragma unroll
    for (int nt = 0; nt < 4; ++nt) {
        float l = lacc[nt];
        l += __shfl_xor(l, 16);
        l += __shfl_xor(l, 32);
        const int q = qbase + wq + nt * 16 + l15;
        #pragma unroll
        for (int dt = 0; dt < 8; ++dt)
            *(float4v*)&Opb[(size_t)q * DIM + dt * 16 + q4] = o_acc[dt][nt];
        if (lane < 16)
            lp[(size_t)(split * 8 + b) * SEQ + q] = l;
    }
}

// ---------------- combine: O = sum(n_s) / sum(l_s) ----------------
template<int NS>
__global__ __launch_bounds__(256)
void combineNS(const float4v* __restrict__ Op, const float* __restrict__ lp,
               float4v* __restrict__ Out) {
    const size_t idx = (size_t)blockIdx.x * 256 + threadIdx.x;
    const size_t srow = idx >> 5;
    float l = 0.0f;
    float4v n = {0.0f, 0.0f, 0.0f, 0.0f};
    #pragma unroll
    for (int s = 0; s < NS; ++s) {
        l += lp[(size_t)s * 8 * SEQ + srow];
        float4v c = Op[idx + (size_t)s * (8ull * SEQ * DIM / 4)];
        n[0] += c[0]; n[1] += c[1]; n[2] += c[2]; n[3] += c[3];
    }
    float inv = 1.0f / l;
    float4v o = {n[0] * inv, n[1] * inv, n[2] * inv, n[3] * inv};
    Out[idx] = o;
}

extern "C" void kernel_launch(void* const* d_in, const int* in_sizes, int n_in,
                              void* d_out, int out_size, void* d_ws, size_t ws_size,
                              hipStream_t stream) {
    const float* Q = (const float*)d_in[0];
    const float* K = (const float*)d_in[1];
    const float* V = (const float*)d_in[2];
    float* O = (float*)d_out;
    char* ws = (char*)d_ws;

    short* Kh  = (short*)ws;
    short* VtG = (short*)(ws + KH_SZ);
    char*  rest = ws + 2 * KH_SZ;
    const size_t need4 = 2 * KH_SZ + 4 * PART + 4 * LPS;

    prepass<<<dim3(8 * (SEQ / 64)), dim3(256), 0, stream>>>(K, V, Kh, VtG);

    if (ws_size >= need4) {
        float* Opp = (float*)rest;
        float* lpp = (float*)(rest + 4 * PART);
        attn_fa7<4><<<dim3(8 * 4 * (SEQ / 128)), dim3(128), 0, stream>>>(Q, Kh, VtG, Opp, lpp);
        combineNS<4><<<dim3((8 * SEQ * DIM / 4) / 256), dim3(256), 0, stream>>>(
            (const float4v*)Opp, lpp, (float4v*)O);
    } else {
        float* Opp = (float*)rest;
        float* lpp = (float*)(rest + 2 * PART);
        attn_fa7<2><<<dim3(8 * 2 * (SEQ / 128)), dim3(128), 0, stream>>>(Q, Kh, VtG, Opp, lpp);
        combineNS<2><<<dim3((8 * SEQ * DIM / 4) / 256), dim3(256), 0, stream>>>(
            (const float4v*)Opp, lpp, (float4v*)O);
    }
}

// Round 10
// 180.284 us; speedup vs baseline: 1.9049x; 1.5194x over previous
//
#include <hip/hip_runtime.h>
#include <cstdint>

#define SEQ 4096
#define DIM 128
#define BK 64
#define PSTR 72    // Ps stride (shorts), aliased inside Ks
#define VSTRP 72   // prepass transpose tile stride

// workspace layout (bytes)
#define KH_SZ  (8ull * SEQ * DIM * 2)
#define PART   (8ull * SEQ * DIM * 4)
#define LPS    (8ull * SEQ * 4)

typedef __attribute__((ext_vector_type(8))) _Float16 half8;
typedef __attribute__((ext_vector_type(2))) __fp16   fp16x2;
typedef __attribute__((ext_vector_type(4))) float  float4v;
typedef __attribute__((ext_vector_type(4))) unsigned int uint4v;
typedef __attribute__((ext_vector_type(2))) unsigned int uint2v;

static __device__ __forceinline__ unsigned int pkh(float a, float b) {
    fp16x2 h = __builtin_amdgcn_cvt_pkrtz(a, b);
    return __builtin_bit_cast(unsigned int, h);
}

// async global->LDS, 16B per lane; LDS dest = wave-uniform base + lane*16
static __device__ __forceinline__ void dma16(const void* g, void* l) {
    __builtin_amdgcn_global_load_lds(
        (const __attribute__((address_space(1))) unsigned int*)g,
        (__attribute__((address_space(3))) unsigned int*)l, 16, 0, 0);
}

// ---------------- prepass: K -> fp16 [b][s][d]; V -> fp16 transposed [b][d][s] ----------------
__global__ __launch_bounds__(256)
void prepass(const float* __restrict__ Kg, const float* __restrict__ Vg,
             short* __restrict__ Kh, short* __restrict__ VtG) {
    __shared__ short Ts[DIM * VSTRP];
    const int t  = threadIdx.x;
    const int b  = blockIdx.x & 7;
    const int s0 = (blockIdx.x >> 3) * 64;

    {   // K tile: coalesced fp32 -> fp16
        const float4v* src = (const float4v*)(Kg + ((size_t)b * SEQ + s0) * DIM);
        uint4v* dst = (uint4v*)(Kh + ((size_t)b * SEQ + s0) * DIM);
        #pragma unroll
        for (int j = 0; j < 4; ++j) {
            int idx = j * 256 + t;
            float4v x0 = src[idx * 2];
            float4v x1 = src[idx * 2 + 1];
            uint4v u;
            u[0] = pkh(x0[0], x0[1]); u[1] = pkh(x0[2], x0[3]);
            u[2] = pkh(x1[0], x1[1]); u[3] = pkh(x1[2], x1[3]);
            dst[idx] = u;
        }
    }
    {   // V tile: 8 keys x 4 d per thread -> Ts[d][key], b128 LDS writes
        const int key8 = (t & 7) * 8;
        const int d0   = (t >> 3) * 4;
        const float* Vsrc = Vg + ((size_t)b * SEQ + s0) * DIM;
        float4v a[8];
        #pragma unroll
        for (int i = 0; i < 8; ++i)
            a[i] = *(const float4v*)&Vsrc[(key8 + i) * DIM + d0];
        #pragma unroll
        for (int e = 0; e < 4; ++e) {
            uint4v pk;
            pk[0] = pkh(a[0][e], a[1][e]);
            pk[1] = pkh(a[2][e], a[3][e]);
            pk[2] = pkh(a[4][e], a[5][e]);
            pk[3] = pkh(a[6][e], a[7][e]);
            *(uint4v*)&Ts[(d0 + e) * VSTRP + key8] = pk;
        }
    }
    __syncthreads();
    #pragma unroll
    for (int j = 0; j < 4; ++j) {   // swizzled read: ~min-conflict
        int idx = j * 256 + t;
        int d = idx >> 3;
        int c = idx & 7;
        int cc = (c + d) & 7;
        uint4v val = *(const uint4v*)&Ts[d * VSTRP + cc * 8];
        *(uint4v*)(VtG + ((size_t)b * DIM + d) * SEQ + s0 + cc * 8) = val;
    }
}

// ---- main: DMA-staged swizzled tiles; S^T = K Q^T -> b64 P stores; PV standard ----
template<int NS>
__global__ __launch_bounds__(128, 2)
void attn_fa8(const float* __restrict__ Qg, const short* __restrict__ Kh,
              const short* __restrict__ VtG, float* __restrict__ Op,
              float* __restrict__ lp) {
    __shared__ short Ks[BK * DIM];   // 16384 B, phys chunk = logical ^ (row&15)
    __shared__ short Vt[DIM * BK];   // 16384 B, phys chunk = logical ^ (d&7)
    short* Ps = Ks;                  // aliased, stride PSTR (9216 B), guarded by B3

    const int t    = threadIdx.x;
    const int w    = t >> 6;
    const int lane = t & 63;
    const int l15  = lane & 15;
    const int quad = lane >> 4;
    const int q8   = quad * 8;
    const int wq   = w * 32;

    const int b     = blockIdx.x & 7;
    const int split = (blockIdx.x >> 3) & (NS - 1);
    const int qbase = (blockIdx.x / (8 * NS)) * 64;

    const short* Khb = Kh + (size_t)b * SEQ * DIM;
    const short* Vtb = VtG + (size_t)b * DIM * SEQ;

    // per-lane swizzled global source pointers for DMA staging
    const short* kgl[4];
    #pragma unroll
    for (int i = 0; i < 4; ++i) {
        int r = w * 32 + i * 4 + (lane >> 4);
        int c = (lane & 15) ^ (r & 15);
        kgl[i] = Khb + (size_t)r * DIM + c * 8;
    }
    const short* vgl;
    {
        int ld = lane >> 3;
        int cv = (lane & 7) ^ (ld & 7);
        vgl = Vtb + (size_t)(w * 64 + ld) * SEQ + cv * 8;
    }
    // swizzled LDS read column offsets (shorts)
    int kcol[4], vcol[2];
    #pragma unroll
    for (int kc = 0; kc < 4; ++kc) kcol[kc] = ((kc * 4 + quad) ^ l15) * 8;
    #pragma unroll
    for (int k2 = 0; k2 < 2; ++k2) vcol[k2] = ((k2 * 4 + quad) ^ (l15 & 7)) * 8;

    const float qs = 0.08838834764831845f * 1.44269504088896340f; // 1/sqrt(128)*log2(e)

    // Q fragments in B-operand layout (n=q=l15, k=dim q8+j), pre-scaled fp16
    half8 qf[2][4];
    {
        const float* Qb = Qg + ((size_t)b * SEQ + qbase + wq) * DIM;
        #pragma unroll
        for (int nt = 0; nt < 2; ++nt) {
            const float* qrow = Qb + (nt * 16 + l15) * DIM;
            #pragma unroll
            for (int kc = 0; kc < 4; ++kc) {
                float4v x0 = *(const float4v*)(qrow + kc * 32 + q8);
                float4v x1 = *(const float4v*)(qrow + kc * 32 + q8 + 4);
                uint4v u;
                u[0] = pkh(x0[0] * qs, x0[1] * qs);
                u[1] = pkh(x0[2] * qs, x0[3] * qs);
                u[2] = pkh(x1[0] * qs, x1[1] * qs);
                u[3] = pkh(x1[2] * qs, x1[3] * qs);
                qf[nt][kc] = __builtin_bit_cast(half8, u);
            }
        }
    }

    const float4v zero4 = {0.0f, 0.0f, 0.0f, 0.0f};
    float4v o_acc[2][8];
    float lacc[2] = {0.0f, 0.0f};
    #pragma unroll
    for (int m = 0; m < 2; ++m)
        #pragma unroll
        for (int n = 0; n < 8; ++n) o_acc[m][n] = zero4;

    for (int kt = 0; kt < 64 / NS; ++kt) {
        const int kbase = (split * (64 / NS) + kt) * BK;
        __syncthreads();   // B1: prior iter's PV reads of Ps/Vt complete

        // DMA staging: K 16KB + V 16KB, swizzled layouts, no VGPR round-trip
        const size_t koff = (size_t)kbase * DIM;
        #pragma unroll
        for (int i = 0; i < 8; ++i)
            dma16(kgl[i & 3] + koff + (size_t)(i >> 2) * (16 * DIM),
                  &Ks[(w * 32 + i * 4) * DIM]);
        #pragma unroll
        for (int i = 0; i < 8; ++i)
            dma16(vgl + (size_t)i * 8 * SEQ + kbase,
                  &Vt[(w * 64 + i * 8) * BK]);
        __syncthreads();   // B2: compiler drains vmcnt before barrier -> tiles visible

        // S^T = K Q^T : lane holds q=l15, keys quad*4+r -> P^T packs to b64
        uint2v pb[4][2];
        #pragma unroll
        for (int mt = 0; mt < 4; ++mt) {
            float4v s0 = zero4, s1 = zero4;
            #pragma unroll
            for (int kc = 0; kc < 4; ++kc) {
                half8 ak = *(const half8*)&Ks[(mt * 16 + l15) * DIM + kcol[kc]];
                s0 = __builtin_amdgcn_mfma_f32_16x16x32_f16(ak, qf[0][kc], s0, 0, 0, 0);
                s1 = __builtin_amdgcn_mfma_f32_16x16x32_f16(ak, qf[1][kc], s1, 0, 0, 0);
            }
            float p0 = __builtin_amdgcn_exp2f(s0[0]), p1 = __builtin_amdgcn_exp2f(s0[1]);
            float p2 = __builtin_amdgcn_exp2f(s0[2]), p3 = __builtin_amdgcn_exp2f(s0[3]);
            lacc[0] += (p0 + p1) + (p2 + p3);
            pb[mt][0][0] = pkh(p0, p1); pb[mt][0][1] = pkh(p2, p3);
            float r0 = __builtin_amdgcn_exp2f(s1[0]), r1 = __builtin_amdgcn_exp2f(s1[1]);
            float r2 = __builtin_amdgcn_exp2f(s1[2]), r3 = __builtin_amdgcn_exp2f(s1[3]);
            lacc[1] += (r0 + r1) + (r2 + r3);
            pb[mt][1][0] = pkh(r0, r1); pb[mt][1][1] = pkh(r2, r3);
        }
        __syncthreads();   // B3: all QK reads of Ks done before Ps overwrites it

        // store P^T: 8 x ds_write_b64 (4 consecutive keys per lane)
        #pragma unroll
        for (int mt = 0; mt < 4; ++mt)
            #pragma unroll
            for (int nt = 0; nt < 2; ++nt)
                *(uint2v*)&Ps[(wq + nt * 16 + l15) * PSTR + mt * 16 + quad * 4] = pb[mt][nt];

        // O += P V  (wave-local Ps rows; lgkmcnt orders write->read)
        #pragma unroll
        for (int k2 = 0; k2 < 2; ++k2) {
            half8 a0 = *(const half8*)&Ps[(wq + l15) * PSTR + k2 * 32 + q8];
            half8 a1 = *(const half8*)&Ps[(wq + 16 + l15) * PSTR + k2 * 32 + q8];
            #pragma unroll
            for (int nt2 = 0; nt2 < 8; ++nt2) {
                half8 bv = *(const half8*)&Vt[(nt2 * 16 + l15) * BK + vcol[k2]];
                o_acc[0][nt2] = __builtin_amdgcn_mfma_f32_16x16x32_f16(a0, bv, o_acc[0][nt2], 0, 0, 0);
                o_acc[1][nt2] = __builtin_amdgcn_mfma_f32_16x16x32_f16(a1, bv, o_acc[1][nt2], 0, 0, 0);
            }
        }
    }

    // epilogue: l(q) = quad-reduce; store UNNORMALIZED partials + l
    float* Opb = Op + ((size_t)(split * 8 + b) * SEQ) * DIM;
    #pragma unroll
    for (int m = 0; m < 2; ++m) {
        float l = lacc[m];
        l += __shfl_xor(l, 16);
        l += __shfl_xor(l, 32);
        const int row0 = qbase + wq + m * 16 + quad * 4;
        #pragma unroll
        for (int r = 0; r < 4; ++r)
            #pragma unroll
            for (int nt2 = 0; nt2 < 8; ++nt2)
                Opb[(size_t)(row0 + r) * DIM + nt2 * 16 + l15] = o_acc[m][nt2][r];
        if (lane < 16)
            lp[(size_t)(split * 8 + b) * SEQ + qbase + wq + m * 16 + lane] = l;
    }
}

// ---------------- combine: O = sum(n_s) / sum(l_s) ----------------
template<int NS>
__global__ __launch_bounds__(256)
void combineNS(const float4v* __restrict__ Op, const float* __restrict__ lp,
               float4v* __restrict__ Out) {
    const size_t idx = (size_t)blockIdx.x * 256 + threadIdx.x;
    const size_t srow = idx >> 5;
    float l = 0.0f;
    float4v n = {0.0f, 0.0f, 0.0f, 0.0f};
    #pragma unroll
    for (int s = 0; s < NS; ++s) {
        l += lp[(size_t)s * 8 * SEQ + srow];
        float4v c = Op[idx + (size_t)s * (8ull * SEQ * DIM / 4)];
        n[0] += c[0]; n[1] += c[1]; n[2] += c[2]; n[3] += c[3];
    }
    float inv = 1.0f / l;
    float4v o = {n[0] * inv, n[1] * inv, n[2] * inv, n[3] * inv};
    Out[idx] = o;
}

extern "C" void kernel_launch(void* const* d_in, const int* in_sizes, int n_in,
                              void* d_out, int out_size, void* d_ws, size_t ws_size,
                              hipStream_t stream) {
    const float* Q = (const float*)d_in[0];
    const float* K = (const float*)d_in[1];
    const float* V = (const float*)d_in[2];
    float* O = (float*)d_out;
    char* ws = (char*)d_ws;

    short* Kh  = (short*)ws;
    short* VtG = (short*)(ws + KH_SZ);
    float* Opp = (float*)(ws + 2 * KH_SZ);
    float* lpp = (float*)(ws + 2 * KH_SZ + 2 * PART);

    prepass<<<dim3(8 * (SEQ / 64)), dim3(256), 0, stream>>>(K, V, Kh, VtG);
    attn_fa8<2><<<dim3(8 * 2 * (SEQ / 64)), dim3(128), 0, stream>>>(Q, Kh, VtG, Opp, lpp);
    combineNS<2><<<dim3((8 * SEQ * DIM / 4) / 256), dim3(256), 0, stream>>>(
        (const float4v*)Opp, lpp, (float4v*)O);
}